// Round 3
// baseline (53.648 us; speedup 1.0000x reference)
//
#include <hip/hip_runtime.h>

// SpikingLinear: 40-step LIF scan over sparse one-shot input spikes.
// R3: snn_k occupancy 2 -> 8 waves/SIMD (NSLICE 8 -> 32, one neuron per lane).
// Latency-bound before (2048 waves); now 8192 waves, same L2 traffic, same
// bit-exact j-ascending summation order per neuron.
//
// Workspace layout (needs ~19.2 MB):
//   [0, 16.78MB)  WT: (IN_DIM+1) x OUT_DIM f32  (row IN_DIM = zero sentinel row)
//   [+0, 2.36MB)  ord: BATCH x ORD_STRIDE int   (byte row-offsets, bucket-sorted)
//   [+0, 42KB)    offs: BATCH x (STEPS+1) int   (padded bucket prefix offsets)

#define IN_DIM     2048
#define OUT_DIM    2048
#define BATCH      256
#define STEPS      40
#define NSLICE     32         // o-slices of 64; XCD x serves slices s%8==x (2MB/L2)
#define ORD_STRIDE 2304       // 2048 + 40*3 (pad) rounded up, 16B-aligned rows

// ---------------- transpose W[O][IN] -> WT[IN][O] (+ zero sentinel row) ------
__global__ __launch_bounds__(256) void transpose_k(const float* __restrict__ W,
                                                   float* __restrict__ WT) {
    __shared__ float tile[64][65];
    const int bx = blockIdx.x;        // input-dim (j) tile
    const int by = blockIdx.y;        // output-dim (o) tile
    const int x  = threadIdx.x & 63;
    const int y4 = threadIdx.x >> 6;  // 0..3
#pragma unroll
    for (int i = 0; i < 16; ++i) {
        const int a = y4 * 16 + i;    // o-local
        tile[a][x] = W[(size_t)(by * 64 + a) * IN_DIM + (bx * 64 + x)];
    }
    // zero the sentinel row (row IN_DIM) -- one block column does it
    if (bx == 0 && y4 == 0)
        WT[(size_t)IN_DIM * OUT_DIM + by * 64 + x] = 0.0f;
    __syncthreads();
#pragma unroll
    for (int i = 0; i < 16; ++i) {
        const int r = y4 * 16 + i;    // j-local
        WT[(size_t)(bx * 64 + r) * OUT_DIM + (by * 64 + x)] = tile[x][r];
    }
}

// ---------------- deterministic stable counting sort per batch ----------------
__global__ __launch_bounds__(256) void sort_k(const float* __restrict__ inp,
                                              int* __restrict__ ord,
                                              int* __restrict__ offs) {
    __shared__ int hist[256 * STEPS];   // per-thread private histograms (40KB)
    __shared__ int tot[STEPS];
    __shared__ int binstart[STEPS + 1];
    const int b = blockIdx.x, t = threadIdx.x;
    for (int i = t; i < 256 * STEPS; i += 256) hist[i] = 0;
    __syncthreads();
    int ks[8];
#pragma unroll
    for (int i = 0; i < 8; ++i) {
        const float v = inp[b * IN_DIM + t * 8 + i];   // = step * 0.5, exact
        const int k = (int)(v * 2.0f);                 // exact integer in fp32
        ks[i] = k;
        ++hist[t * STEPS + k];
    }
    __syncthreads();
    // exclusive prefix over threads, per bin (stable order = ascending j)
    if (t < STEPS) {
        int run = 0;
        for (int tt = 0; tt < 256; ++tt) {
            const int c = hist[tt * STEPS + t];
            hist[tt * STEPS + t] = run;
            run += c;
        }
        tot[t] = run;
    }
    __syncthreads();
    if (t == 0) {
        int run = 0;
        for (int k = 0; k < STEPS; ++k) {
            binstart[k] = run;
            run += (tot[k] + 3) & ~3;   // pad each bucket to multiple of 4
        }
        binstart[STEPS] = run;
    }
    __syncthreads();
    if (t <= STEPS) offs[b * (STEPS + 1) + t] = binstart[t];
    // scatter real entries (premultiplied byte row offsets)
#pragma unroll
    for (int i = 0; i < 8; ++i) {
        const int k = ks[i];
        const int pos = binstart[k] + hist[t * STEPS + k]++;
        ord[b * ORD_STRIDE + pos] = (t * 8 + i) * (OUT_DIM * 4);
    }
    // sentinel padding -> zero row (row index IN_DIM); adding 0.0f is exact
    if (t < STEPS) {
        const int beg = binstart[t] + tot[t];
        const int end = binstart[t] + ((tot[t] + 3) & ~3);
        for (int p = beg; p < end; ++p)
            ord[b * ORD_STRIDE + p] = IN_DIM * (OUT_DIM * 4);
    }
}

// ---------------- main LIF kernel: one wave per (batch, 64-output slice) ------
__global__ __launch_bounds__(64) void snn_k(const float* __restrict__ WT,
                                            const int* __restrict__ ord,
                                            const int* __restrict__ offs,
                                            float* __restrict__ out) {
    const int wid  = blockIdx.x;
    const int s    = wid & (NSLICE - 1);   // slice; s%8 tracks XCD round-robin
    const int b    = wid >> 5;
    const int lane = threadIdx.x;
    const char* wb = (const char*)(WT + s * 64 + lane);
    const int* __restrict__ ob  = ord  + b * ORD_STRIDE;
    const int* __restrict__ off = offs + b * (STEPS + 1);

    float I = 0.f, V = 0.f;
    int   f = 0;
    int p = 0;
    for (int k = 0; k < STEPS; ++k) {
        const int e = off[k + 1];
        float a = 0.f;
        for (; p < e; p += 4) {
            const int4 jj = *(const int4*)(ob + p);   // wave-uniform
            // j-ascending order (bit-exact vs reference bucket order)
            a += *(const float*)(wb + jj.x);
            a += *(const float*)(wb + jj.y);
            a += *(const float*)(wb + jj.z);
            a += *(const float*)(wb + jj.w);
        }
        // V uses I from previous step, then I update, then spike check (ref order)
        V += 0.025f * (I - V);
        I = 0.9f * I + a;
        if (V > 1.0f) { if (f == 0) f = k; V = 0.f; }
        if (__all(f != 0)) break;
    }
    out[(size_t)b * OUT_DIM + s * 64 + lane] = f ? (float)f : 20.0f;
}

extern "C" void kernel_launch(void* const* d_in, const int* in_sizes, int n_in,
                              void* d_out, int out_size, void* d_ws, size_t ws_size,
                              hipStream_t stream) {
    const float* inp = (const float*)d_in[0];
    const float* W   = (const float*)d_in[1];
    float* out = (float*)d_out;
    char*  ws  = (char*)d_ws;

    float* WT = (float*)ws;                                   // (IN_DIM+1) rows
    const size_t WT_BYTES = (size_t)(IN_DIM + 1) * OUT_DIM * sizeof(float);
    int* ord  = (int*)(ws + WT_BYTES);
    int* offs = (int*)(ws + WT_BYTES + (size_t)BATCH * ORD_STRIDE * sizeof(int));

    transpose_k<<<dim3(IN_DIM / 64, OUT_DIM / 64), 256, 0, stream>>>(W, WT);
    sort_k<<<BATCH, 256, 0, stream>>>(inp, ord, offs);
    snn_k<<<BATCH * NSLICE, 64, 0, stream>>>(WT, ord, offs, out);
}

// Round 4
// 45.780 us; speedup vs baseline: 1.1719x; 1.1719x over previous
//
#include <hip/hip_runtime.h>

// SpikingLinear: 40-step LIF scan over sparse one-shot input spikes.
// R4: (a) sort's serial 256-iter LDS prefix -> two-level parallel scan
//     (160 workers x 64-elem chunks, unroll-8); (b) transpose+sort merged
//     into one dispatch (independent work, fewer graph boundaries).
//     snn_k unchanged as control (hypothesis: it sits at ~22us L2-BW floor).
//
// Workspace layout (needs ~19.2 MB):
//   [0, 16.78MB)  WT: (IN_DIM+1) x OUT_DIM f32  (row IN_DIM = zero sentinel row)
//   [+0, 2.36MB)  ord: BATCH x ORD_STRIDE int   (byte row-offsets, bucket-sorted)
//   [+0, 42KB)    offs: BATCH x (STEPS+1) int   (padded bucket prefix offsets)

#define IN_DIM     2048
#define OUT_DIM    2048
#define BATCH      256
#define STEPS      40
#define NSLICE     32         // o-slices of 64; XCD x serves slices s%8==x (2MB/L2)
#define ORD_STRIDE 2304       // 2048 + 40*3 (pad) rounded up, 16B-aligned rows

// ---------------- fused prep: blocks [0,256) sort, [256,1280) transpose ------
__global__ __launch_bounds__(256) void prep_k(const float* __restrict__ W,
                                              float* __restrict__ WT,
                                              const float* __restrict__ inp,
                                              int* __restrict__ ord,
                                              int* __restrict__ offs) {
    __shared__ __align__(16) char smem[43008];
    const int t = threadIdx.x;

    if (blockIdx.x >= BATCH) {
        // ---- transpose W[O][IN] -> WT[IN][O] (+ zero sentinel row) ----
        float (*tile)[65] = (float (*)[65])smem;
        const int id = blockIdx.x - BATCH;
        const int bx = id & 31;          // input-dim (j) tile
        const int by = id >> 5;          // output-dim (o) tile
        const int x  = t & 63;
        const int y4 = t >> 6;           // 0..3
#pragma unroll
        for (int i = 0; i < 16; ++i) {
            const int a = y4 * 16 + i;   // o-local
            tile[a][x] = W[(size_t)(by * 64 + a) * IN_DIM + (bx * 64 + x)];
        }
        if (bx == 0 && y4 == 0)
            WT[(size_t)IN_DIM * OUT_DIM + by * 64 + x] = 0.0f;
        __syncthreads();
#pragma unroll
        for (int i = 0; i < 16; ++i) {
            const int r = y4 * 16 + i;   // j-local
            WT[(size_t)(bx * 64 + r) * OUT_DIM + (by * 64 + x)] = tile[x][r];
        }
        return;
    }

    // ---- deterministic stable counting sort for batch b ----
    int* hist     = (int*)smem;                    // [256][STEPS]  40960 B
    int* chunkcnt = (int*)(smem + 40960);          // [STEPS][4]      640 B
    int* binstart = (int*)(smem + 40960 + 640);    // [STEPS+1]       164 B
    int* tot      = (int*)(smem + 40960 + 640 + 164); // [STEPS]      160 B
    const int b = blockIdx.x;

    for (int i = t; i < 256 * STEPS; i += 256) hist[i] = 0;
    __syncthreads();
    int ks[8];
#pragma unroll
    for (int i = 0; i < 8; ++i) {
        const float v = inp[b * IN_DIM + t * 8 + i];   // = step * 0.5, exact
        const int k = (int)(v * 2.0f);                 // exact integer in fp32
        ks[i] = k;
        ++hist[t * STEPS + k];
    }
    __syncthreads();
    // level 1: worker (k,q) sums its 64-thread chunk of bin k (batched loads)
    if (t < STEPS * 4) {
        const int k = t >> 2, q = t & 3;
        int run = 0;
#pragma unroll
        for (int i = 0; i < 64; i += 8) {
            const int base = (q * 64 + i) * STEPS + k;
            const int c0 = hist[base + 0 * STEPS], c1 = hist[base + 1 * STEPS];
            const int c2 = hist[base + 2 * STEPS], c3 = hist[base + 3 * STEPS];
            const int c4 = hist[base + 4 * STEPS], c5 = hist[base + 5 * STEPS];
            const int c6 = hist[base + 6 * STEPS], c7 = hist[base + 7 * STEPS];
            run += ((c0 + c1) + (c2 + c3)) + ((c4 + c5) + (c6 + c7));
        }
        chunkcnt[k * 4 + q] = run;
    }
    __syncthreads();
    // level 2: tiny serial combine across 40 bins (padded to multiple of 4)
    if (t == 0) {
        int run = 0;
        for (int k = 0; k < STEPS; ++k) {
            binstart[k] = run;
            const int tk = (chunkcnt[k * 4] + chunkcnt[k * 4 + 1]) +
                           (chunkcnt[k * 4 + 2] + chunkcnt[k * 4 + 3]);
            tot[k] = tk;
            run += (tk + 3) & ~3;
        }
        binstart[STEPS] = run;
    }
    __syncthreads();
    if (t <= STEPS) offs[b * (STEPS + 1) + t] = binstart[t];
    // level 3: worker (k,q) rewrites its chunk as global exclusive prefixes
    if (t < STEPS * 4) {
        const int k = t >> 2, q = t & 3;
        int run = binstart[k];
        for (int qq = 0; qq < q; ++qq) run += chunkcnt[k * 4 + qq];
#pragma unroll 8
        for (int i = 0; i < 64; ++i) {
            const int a = (q * 64 + i) * STEPS + k;
            const int c = hist[a];
            hist[a] = run;
            run += c;
        }
    }
    __syncthreads();
    // scatter real entries (premultiplied byte row offsets), j-ascending stable
#pragma unroll
    for (int i = 0; i < 8; ++i) {
        const int k = ks[i];
        const int pos = hist[t * STEPS + k]++;
        ord[b * ORD_STRIDE + pos] = (t * 8 + i) * (OUT_DIM * 4);
    }
    // sentinel padding -> zero row (row index IN_DIM); adding 0.0f is exact
    if (t < STEPS) {
        const int beg = binstart[t] + tot[t];
        const int end = binstart[t] + ((tot[t] + 3) & ~3);
        for (int p = beg; p < end; ++p)
            ord[b * ORD_STRIDE + p] = IN_DIM * (OUT_DIM * 4);
    }
}

// ---------------- main LIF kernel: one wave per (batch, 64-output slice) ------
__global__ __launch_bounds__(64) void snn_k(const float* __restrict__ WT,
                                            const int* __restrict__ ord,
                                            const int* __restrict__ offs,
                                            float* __restrict__ out) {
    const int wid  = blockIdx.x;
    const int s    = wid & (NSLICE - 1);   // slice; s%8 tracks XCD round-robin
    const int b    = wid >> 5;
    const int lane = threadIdx.x;
    const char* wb = (const char*)(WT + s * 64 + lane);
    const int* __restrict__ ob  = ord  + b * ORD_STRIDE;
    const int* __restrict__ off = offs + b * (STEPS + 1);

    float I = 0.f, V = 0.f;
    int   f = 0;
    int p = 0;
    for (int k = 0; k < STEPS; ++k) {
        const int e = off[k + 1];
        float a = 0.f;
        for (; p < e; p += 4) {
            const int4 jj = *(const int4*)(ob + p);   // wave-uniform
            // j-ascending order (bit-exact vs reference bucket order)
            a += *(const float*)(wb + jj.x);
            a += *(const float*)(wb + jj.y);
            a += *(const float*)(wb + jj.z);
            a += *(const float*)(wb + jj.w);
        }
        // V uses I from previous step, then I update, then spike check (ref order)
        V += 0.025f * (I - V);
        I = 0.9f * I + a;
        if (V > 1.0f) { if (f == 0) f = k; V = 0.f; }
        if (__all(f != 0)) break;
    }
    out[(size_t)b * OUT_DIM + s * 64 + lane] = f ? (float)f : 20.0f;
}

extern "C" void kernel_launch(void* const* d_in, const int* in_sizes, int n_in,
                              void* d_out, int out_size, void* d_ws, size_t ws_size,
                              hipStream_t stream) {
    const float* inp = (const float*)d_in[0];
    const float* W   = (const float*)d_in[1];
    float* out = (float*)d_out;
    char*  ws  = (char*)d_ws;

    float* WT = (float*)ws;                                   // (IN_DIM+1) rows
    const size_t WT_BYTES = (size_t)(IN_DIM + 1) * OUT_DIM * sizeof(float);
    int* ord  = (int*)(ws + WT_BYTES);
    int* offs = (int*)(ws + WT_BYTES + (size_t)BATCH * ORD_STRIDE * sizeof(int));

    prep_k<<<BATCH + (IN_DIM / 64) * (OUT_DIM / 64), 256, 0, stream>>>(W, WT, inp, ord, offs);
    snn_k<<<BATCH * NSLICE, 64, 0, stream>>>(WT, ord, offs, out);
}